// Round 1
// baseline (817.684 us; speedup 1.0000x reference)
//
#include <hip/hip_runtime.h>
#include <hip/hip_bf16.h>
#include <cstdint>

#define N_NODES 50000
#define N_EDGES 640000
#define IN_DIM 128
#define HID_DIM 128
#define OUT_DIM 64

static __device__ __forceinline__ int detect_i64(const void* p) {
    // If edge_index is int64 (values < 2^31), every odd int32 word is a zero
    // high-word. Probability of false positive with real int32 data ~ (1/50000)^32.
    const int* q = (const int*)p;
    int odd_or = 0, even_or = 0;
#pragma unroll
    for (int i = 1; i < 64; i += 2) odd_or |= q[i];
#pragma unroll
    for (int i = 0; i < 64; i += 2) even_or |= q[i];
    return (odd_or == 0 && even_or != 0) ? 1 : 0;
}

__global__ void k_convert_edges(const void* __restrict__ ei,
                                int* __restrict__ rows, int* __restrict__ cols,
                                int n_edges) {
    __shared__ int is64_s;
    if (threadIdx.x == 0) is64_s = detect_i64(ei);
    __syncthreads();
    int is64 = is64_s;
    int e = blockIdx.x * blockDim.x + threadIdx.x;
    if (e >= n_edges) return;
    if (is64) {
        const long long* q = (const long long*)ei;
        rows[e] = (int)q[e];
        cols[e] = (int)q[e + n_edges];
    } else {
        const int* q = (const int*)ei;
        rows[e] = q[e];
        cols[e] = q[e + n_edges];
    }
}

__global__ void k_fill_deg(float* __restrict__ deg, int n) {
    int i = blockIdx.x * blockDim.x + threadIdx.x;
    if (i < n) deg[i] = 1.0f;  // self-loop weight
}

__global__ void k_deg_accum(const int* __restrict__ cols,
                            const float* __restrict__ w,
                            float* __restrict__ deg, int n_edges) {
    int e = blockIdx.x * blockDim.x + threadIdx.x;
    if (e < n_edges) atomicAdd(&deg[cols[e]], w[e]);
}

__global__ void k_dinv(float* __restrict__ deg, float* __restrict__ dinv, int n) {
    int i = blockIdx.x * blockDim.x + threadIdx.x;
    if (i < n) {
        float d = deg[i];
        dinv[i] = d > 0.f ? rsqrtf(d) : 0.f;
    }
}

__global__ void k_norm(const int* __restrict__ rows, const int* __restrict__ cols,
                       const float* __restrict__ w, const float* __restrict__ dinv,
                       float* __restrict__ norm, int n_edges) {
    int e = blockIdx.x * blockDim.x + threadIdx.x;
    if (e < n_edges) norm[e] = dinv[rows[e]] * w[e] * dinv[cols[e]];
}

// C[n, DOUT] = A[n, 128] @ W[128, DOUT], optional ReLU applied to A on load.
template <int DOUT, bool RELU_IN>
__global__ __launch_bounds__(DOUT) void k_gemm(const float* __restrict__ A,
                                               const float* __restrict__ W,
                                               float* __restrict__ C, int n) {
    constexpr int RPB = 16;  // rows per block
    __shared__ float as[RPB][IN_DIM];
    int row0 = blockIdx.x * RPB;
    int j = threadIdx.x;
    for (int t = threadIdx.x; t < RPB * IN_DIM; t += DOUT) {
        int r = t >> 7, k = t & 127;
        float v = (row0 + r < n) ? A[(size_t)(row0 + r) * IN_DIM + k] : 0.f;
        if (RELU_IN) v = fmaxf(v, 0.f);
        as[r][k] = v;
    }
    __syncthreads();
    float acc[RPB];
#pragma unroll
    for (int r = 0; r < RPB; r++) acc[r] = 0.f;
    for (int k = 0; k < IN_DIM; k++) {
        float w = W[k * DOUT + j];
#pragma unroll
        for (int r = 0; r < RPB; r++) acc[r] += as[r][k] * w;
    }
#pragma unroll
    for (int r = 0; r < RPB; r++) {
        if (row0 + r < n) C[(size_t)(row0 + r) * DOUT + j] = acc[r];
    }
}

// out[i][j] = htmp[i][j] * dinv[i]^2 + b[j]   (self-loop message + bias)
template <int D>
__global__ void k_self_init(const float* __restrict__ htmp,
                            const float* __restrict__ dinv,
                            const float* __restrict__ b,
                            float* __restrict__ out, int n) {
    int idx = blockIdx.x * blockDim.x + threadIdx.x;
    if (idx >= n * D) return;
    int i = idx / D, j = idx % D;
    float di = dinv[i];
    out[idx] = htmp[idx] * di * di + b[j];
}

// One wave per edge: out[col] += htmp[row] * norm
template <int D>
__global__ void k_scatter(const float* __restrict__ htmp,
                          const int* __restrict__ rows,
                          const int* __restrict__ cols,
                          const float* __restrict__ norm,
                          float* __restrict__ out, int n_edges) {
    int wid = (int)((blockIdx.x * (size_t)blockDim.x + threadIdx.x) >> 6);
    int lane = threadIdx.x & 63;
    if (wid >= n_edges) return;
    int r = rows[wid];
    int c = cols[wid];
    float nm = norm[wid];
    if constexpr (D == 128) {
        float2 v = *(const float2*)&htmp[(size_t)r * 128 + lane * 2];
        atomicAdd(&out[(size_t)c * 128 + lane * 2 + 0], v.x * nm);
        atomicAdd(&out[(size_t)c * 128 + lane * 2 + 1], v.y * nm);
    } else {
        float v = htmp[(size_t)r * 64 + lane];
        atomicAdd(&out[(size_t)c * 64 + lane], v * nm);
    }
}

static inline size_t align_up(size_t x, size_t a) { return (x + a - 1) & ~(a - 1); }

extern "C" void kernel_launch(void* const* d_in, const int* in_sizes, int n_in,
                              void* d_out, int out_size, void* d_ws, size_t ws_size,
                              hipStream_t stream) {
    const float* x  = (const float*)d_in[0];
    const void*  ei = d_in[1];
    const float* ew = (const float*)d_in[2];
    const float* W1 = (const float*)d_in[3];
    const float* b1 = (const float*)d_in[4];
    const float* W2 = (const float*)d_in[5];
    const float* b2 = (const float*)d_in[6];
    float* out = (float*)d_out;

    const int N = N_NODES, E = N_EDGES;

    char* p = (char*)d_ws;
    int*   rows = (int*)p;   p += align_up((size_t)E * 4, 512);
    int*   cols = (int*)p;   p += align_up((size_t)E * 4, 512);
    float* deg  = (float*)p; p += align_up((size_t)N * 4, 512);
    float* dinv = (float*)p; p += align_up((size_t)N * 4, 512);
    float* norm = (float*)p; p += align_up((size_t)E * 4, 512);
    float* htmp = (float*)p; p += align_up((size_t)N * IN_DIM * 4, 512);
    float* h1   = (float*)p; p += align_up((size_t)N * HID_DIM * 4, 512);
    (void)ws_size;

    const int B = 256;
    int gE = (E + B - 1) / B;
    int gN = (N + B - 1) / B;

    // ---- norm precompute ----
    k_convert_edges<<<gE, B, 0, stream>>>(ei, rows, cols, E);
    k_fill_deg<<<gN, B, 0, stream>>>(deg, N);
    k_deg_accum<<<gE, B, 0, stream>>>(cols, ew, deg, E);
    k_dinv<<<gN, B, 0, stream>>>(deg, dinv, N);
    k_norm<<<gE, B, 0, stream>>>(rows, cols, ew, dinv, norm, E);

    // ---- layer 1: h1 = relu-later( (x@W1) aggregated + b1 ) ----
    int gemm_blocks = (N + 15) / 16;
    k_gemm<HID_DIM, false><<<gemm_blocks, HID_DIM, 0, stream>>>(x, W1, htmp, N);
    k_self_init<HID_DIM><<<(N * HID_DIM + B - 1) / B, B, 0, stream>>>(htmp, dinv, b1, h1, N);
    k_scatter<HID_DIM><<<(E * 64 + B - 1) / B, B, 0, stream>>>(htmp, rows, cols, norm, h1, E);
    // ReLU is fused into layer-2 GEMM's A-load.

    // ---- layer 2: out = (relu(h1)@W2) aggregated + b2 ----
    k_gemm<OUT_DIM, true><<<gemm_blocks, OUT_DIM, 0, stream>>>(h1, W2, htmp, N);
    k_self_init<OUT_DIM><<<(N * OUT_DIM + B - 1) / B, B, 0, stream>>>(htmp, dinv, b2, out, N);
    k_scatter<OUT_DIM><<<(E * 64 + B - 1) / B, B, 0, stream>>>(htmp, rows, cols, norm, out, E);
    (void)out_size; (void)n_in; (void)in_sizes;
}

// Round 2
// 335.126 us; speedup vs baseline: 2.4399x; 2.4399x over previous
//
#include <hip/hip_runtime.h>
#include <hip/hip_bf16.h>
#include <cstdint>

#define N_NODES 50000
#define N_EDGES 640000
#define IN_DIM 128
#define HID_DIM 128
#define OUT_DIM 64

static __device__ __forceinline__ int detect_i64(const void* p) {
    // int64 edge_index (values < 2^31) => every odd int32 word is a zero high-word.
    const int* q = (const int*)p;
    int odd_or = 0, even_or = 0;
#pragma unroll
    for (int i = 1; i < 64; i += 2) odd_or |= q[i];
#pragma unroll
    for (int i = 0; i < 64; i += 2) even_or |= q[i];
    return (odd_or == 0 && even_or != 0) ? 1 : 0;
}

__global__ void k_convert_edges(const void* __restrict__ ei,
                                int* __restrict__ rows, int* __restrict__ cols,
                                int n_edges) {
    __shared__ int is64_s;
    if (threadIdx.x == 0) is64_s = detect_i64(ei);
    __syncthreads();
    int is64 = is64_s;
    int e = blockIdx.x * blockDim.x + threadIdx.x;
    if (e >= n_edges) return;
    if (is64) {
        const long long* q = (const long long*)ei;
        rows[e] = (int)q[e];
        cols[e] = (int)q[e + n_edges];
    } else {
        const int* q = (const int*)ei;
        rows[e] = q[e];
        cols[e] = q[e + n_edges];
    }
}

// deg=1 (self loop), counts=0, cursor=0
__global__ void k_init_nodes(float* __restrict__ deg, int* __restrict__ counts,
                             int* __restrict__ cursor, int n) {
    int i = blockIdx.x * blockDim.x + threadIdx.x;
    if (i < n) { deg[i] = 1.0f; counts[i] = 0; cursor[i] = 0; }
}

// deg[col] += w ; counts[col] += 1  (fused histogram)
__global__ void k_deg_hist(const int* __restrict__ cols, const float* __restrict__ w,
                           float* __restrict__ deg, int* __restrict__ counts, int n_edges) {
    int e = blockIdx.x * blockDim.x + threadIdx.x;
    if (e < n_edges) {
        int c = cols[e];
        atomicAdd(&deg[c], w[e]);
        atomicAdd(&counts[c], 1);
    }
}

__global__ void k_dinv(const float* __restrict__ deg, float* __restrict__ dinv, int n) {
    int i = blockIdx.x * blockDim.x + threadIdx.x;
    if (i < n) {
        float d = deg[i];
        dinv[i] = d > 0.f ? rsqrtf(d) : 0.f;
    }
}

__global__ void k_norm(const int* __restrict__ rows, const int* __restrict__ cols,
                       const float* __restrict__ w, const float* __restrict__ dinv,
                       float* __restrict__ norm, int n_edges) {
    int e = blockIdx.x * blockDim.x + threadIdx.x;
    if (e < n_edges) norm[e] = dinv[rows[e]] * w[e] * dinv[cols[e]];
}

// ---- hierarchical exclusive scan over counts[n] -> starts[n+1] ----
__global__ void k_scan_block(const int* __restrict__ counts, int* __restrict__ starts,
                             int* __restrict__ bsums, int n) {
    __shared__ int buf[256];
    int i = blockIdx.x * 256 + threadIdx.x;
    int v = (i < n) ? counts[i] : 0;
    buf[threadIdx.x] = v;
    __syncthreads();
#pragma unroll
    for (int off = 1; off < 256; off <<= 1) {
        int t = (threadIdx.x >= off) ? buf[threadIdx.x - off] : 0;
        __syncthreads();
        buf[threadIdx.x] += t;
        __syncthreads();
    }
    if (i < n) starts[i] = buf[threadIdx.x] - v;  // exclusive within block
    if (threadIdx.x == 255) bsums[blockIdx.x] = buf[255];
}

__global__ void k_scan_tops(int* __restrict__ bsums, int nb) {
    __shared__ int buf[256];
    int v = (threadIdx.x < nb) ? bsums[threadIdx.x] : 0;
    buf[threadIdx.x] = v;
    __syncthreads();
#pragma unroll
    for (int off = 1; off < 256; off <<= 1) {
        int t = (threadIdx.x >= off) ? buf[threadIdx.x - off] : 0;
        __syncthreads();
        buf[threadIdx.x] += t;
        __syncthreads();
    }
    if (threadIdx.x < nb) bsums[threadIdx.x] = buf[threadIdx.x] - v;  // exclusive
}

__global__ void k_scan_add(int* __restrict__ starts, const int* __restrict__ bsums,
                           int n, int total) {
    int i = blockIdx.x * 256 + threadIdx.x;
    if (i < n) starts[i] += bsums[blockIdx.x];
    if (i == 0) starts[n] = total;
}

// counting-sort fill: packed[pos] = {row, norm}
__global__ void k_fill_csr(const int* __restrict__ rows, const int* __restrict__ cols,
                           const float* __restrict__ norm, const int* __restrict__ starts,
                           int* __restrict__ cursor, int2* __restrict__ packed, int n_edges) {
    int e = blockIdx.x * blockDim.x + threadIdx.x;
    if (e >= n_edges) return;
    int c = cols[e];
    int pos = starts[c] + atomicAdd(&cursor[c], 1);
    packed[pos] = make_int2(rows[e], __float_as_int(norm[e]));
}

// C[n, DOUT] = A[n, 128] @ W[128, DOUT], optional ReLU applied to A on load.
template <int DOUT, bool RELU_IN>
__global__ __launch_bounds__(DOUT) void k_gemm(const float* __restrict__ A,
                                               const float* __restrict__ W,
                                               float* __restrict__ C, int n) {
    constexpr int RPB = 16;  // rows per block
    __shared__ float as[RPB][IN_DIM];
    int row0 = blockIdx.x * RPB;
    int j = threadIdx.x;
    for (int t = threadIdx.x; t < RPB * IN_DIM; t += DOUT) {
        int r = t >> 7, k = t & 127;
        float v = (row0 + r < n) ? A[(size_t)(row0 + r) * IN_DIM + k] : 0.f;
        if (RELU_IN) v = fmaxf(v, 0.f);
        as[r][k] = v;
    }
    __syncthreads();
    float acc[RPB];
#pragma unroll
    for (int r = 0; r < RPB; r++) acc[r] = 0.f;
    for (int k = 0; k < IN_DIM; k++) {
        float w = W[k * DOUT + j];
#pragma unroll
        for (int r = 0; r < RPB; r++) acc[r] += as[r][k] * w;
    }
#pragma unroll
    for (int r = 0; r < RPB; r++) {
        if (row0 + r < n) C[(size_t)(row0 + r) * DOUT + j] = acc[r];
    }
}

// One wave per node: out[c] = htmp[c]*dinv[c]^2 + b + sum_{edges->c} htmp[row]*norm
template <int D>
__global__ void k_gather(const float* __restrict__ htmp, const int2* __restrict__ packed,
                         const int* __restrict__ starts, const float* __restrict__ dinv,
                         const float* __restrict__ b, float* __restrict__ out, int n) {
    int wid = (int)((blockIdx.x * (size_t)blockDim.x + threadIdx.x) >> 6);
    int lane = threadIdx.x & 63;
    if (wid >= n) return;
    int c = wid;
    int beg = starts[c], end = starts[c + 1];
    float di = dinv[c];
    float s = di * di;
    if constexpr (D == 128) {
        int j = lane * 2;
        float2 hv = *(const float2*)&htmp[(size_t)c * 128 + j];
        float2 acc;
        acc.x = hv.x * s + b[j];
        acc.y = hv.y * s + b[j + 1];
        for (int p = beg; p < end; ++p) {
            int2 rn = packed[p];
            float nm = __int_as_float(rn.y);
            float2 v = *(const float2*)&htmp[(size_t)rn.x * 128 + j];
            acc.x += v.x * nm;
            acc.y += v.y * nm;
        }
        *(float2*)&out[(size_t)c * 128 + j] = acc;
    } else {
        int j = lane;
        float acc = htmp[(size_t)c * 64 + j] * s + b[j];
        for (int p = beg; p < end; ++p) {
            int2 rn = packed[p];
            float nm = __int_as_float(rn.y);
            acc += htmp[(size_t)rn.x * 64 + j] * nm;
        }
        out[(size_t)c * 64 + j] = acc;
    }
}

static inline size_t align_up(size_t x, size_t a) { return (x + a - 1) & ~(a - 1); }

extern "C" void kernel_launch(void* const* d_in, const int* in_sizes, int n_in,
                              void* d_out, int out_size, void* d_ws, size_t ws_size,
                              hipStream_t stream) {
    const float* x  = (const float*)d_in[0];
    const void*  ei = d_in[1];
    const float* ew = (const float*)d_in[2];
    const float* W1 = (const float*)d_in[3];
    const float* b1 = (const float*)d_in[4];
    const float* W2 = (const float*)d_in[5];
    const float* b2 = (const float*)d_in[6];
    float* out = (float*)d_out;

    const int N = N_NODES, E = N_EDGES;

    char* p = (char*)d_ws;
    int*   rows   = (int*)p;   p += align_up((size_t)E * 4, 512);
    int*   cols   = (int*)p;   p += align_up((size_t)E * 4, 512);
    float* deg    = (float*)p; p += align_up((size_t)N * 4, 512);
    float* dinv   = (float*)p; p += align_up((size_t)N * 4, 512);
    float* norm   = (float*)p; p += align_up((size_t)E * 4, 512);
    int*   counts = (int*)p;   p += align_up((size_t)N * 4, 512);
    int*   starts = (int*)p;   p += align_up((size_t)(N + 1) * 4, 512);
    int*   cursor = (int*)p;   p += align_up((size_t)N * 4, 512);
    int*   bsums  = (int*)p;   p += align_up((size_t)256 * 4, 512);
    int2*  packed = (int2*)p;  p += align_up((size_t)E * 8, 512);
    float* htmp   = (float*)p; p += align_up((size_t)N * IN_DIM * 4, 512);
    float* h1     = (float*)p; p += align_up((size_t)N * HID_DIM * 4, 512);
    (void)ws_size;

    const int B = 256;
    int gE = (E + B - 1) / B;
    int gN = (N + B - 1) / B;
    int nb = (N + 255) / 256;  // 196 blocks for the scan

    // ---- norm + CSR precompute ----
    k_convert_edges<<<gE, B, 0, stream>>>(ei, rows, cols, E);
    k_init_nodes<<<gN, B, 0, stream>>>(deg, counts, cursor, N);
    k_deg_hist<<<gE, B, 0, stream>>>(cols, ew, deg, counts, E);
    k_dinv<<<gN, B, 0, stream>>>(deg, dinv, N);
    k_norm<<<gE, B, 0, stream>>>(rows, cols, ew, dinv, norm, E);
    k_scan_block<<<nb, 256, 0, stream>>>(counts, starts, bsums, N);
    k_scan_tops<<<1, 256, 0, stream>>>(bsums, nb);
    k_scan_add<<<nb, 256, 0, stream>>>(starts, bsums, N, E);
    k_fill_csr<<<gE, B, 0, stream>>>(rows, cols, norm, starts, cursor, packed, E);

    // ---- layer 1 ----
    int gemm_blocks = (N + 15) / 16;
    k_gemm<HID_DIM, false><<<gemm_blocks, HID_DIM, 0, stream>>>(x, W1, htmp, N);
    k_gather<HID_DIM><<<((size_t)N * 64 + B - 1) / B, B, 0, stream>>>(htmp, packed, starts, dinv, b1, h1, N);
    // ReLU fused into layer-2 GEMM's A-load.

    // ---- layer 2 ----
    k_gemm<OUT_DIM, true><<<gemm_blocks, OUT_DIM, 0, stream>>>(h1, W2, htmp, N);
    k_gather<OUT_DIM><<<((size_t)N * 64 + B - 1) / B, B, 0, stream>>>(htmp, packed, starts, dinv, b2, out, N);
    (void)out_size; (void)n_in; (void)in_sizes;
}

// Round 3
// 290.025 us; speedup vs baseline: 2.8194x; 1.1555x over previous
//
#include <hip/hip_runtime.h>
#include <hip/hip_bf16.h>
#include <cstdint>

#define N_NODES 50000
#define N_EDGES 640000
#define IN_DIM 128
#define HID_DIM 128
#define OUT_DIM 64

static __device__ __forceinline__ int detect_i64(const void* p) {
    // int64 edge_index (values < 2^31) => every odd int32 word is a zero high-word.
    const int* q = (const int*)p;
    int odd_or = 0, even_or = 0;
#pragma unroll
    for (int i = 1; i < 64; i += 2) odd_or |= q[i];
#pragma unroll
    for (int i = 0; i < 64; i += 2) even_or |= q[i];
    return (odd_or == 0 && even_or != 0) ? 1 : 0;
}

// deg=1 (self loop), counts=0, cursor=0
__global__ void k_init_nodes(float* __restrict__ deg, int* __restrict__ counts,
                             int* __restrict__ cursor, int n) {
    int i = blockIdx.x * blockDim.x + threadIdx.x;
    if (i < n) { deg[i] = 1.0f; counts[i] = 0; cursor[i] = 0; }
}

// convert edge_index (+layout sniff) -> rows/cols, and histogram deg/counts
__global__ void k_edges_hist(const void* __restrict__ ei, const float* __restrict__ w,
                             int* __restrict__ rows, int* __restrict__ cols,
                             float* __restrict__ deg, int* __restrict__ counts,
                             int n_edges) {
    __shared__ int is64_s;
    if (threadIdx.x == 0) is64_s = detect_i64(ei);
    __syncthreads();
    int e = blockIdx.x * blockDim.x + threadIdx.x;
    if (e >= n_edges) return;
    int r, c;
    if (is64_s) {
        const long long* q = (const long long*)ei;
        r = (int)q[e];
        c = (int)q[e + n_edges];
    } else {
        const int* q = (const int*)ei;
        r = q[e];
        c = q[e + n_edges];
    }
    rows[e] = r;
    cols[e] = c;
    atomicAdd(&deg[c], w[e]);
    atomicAdd(&counts[c], 1);
}

__global__ void k_dinv(const float* __restrict__ deg, float* __restrict__ dinv, int n) {
    int i = blockIdx.x * blockDim.x + threadIdx.x;
    if (i < n) {
        float d = deg[i];
        dinv[i] = d > 0.f ? rsqrtf(d) : 0.f;
    }
}

// ---- hierarchical exclusive scan over counts[n] -> starts[n+1] ----
__global__ void k_scan_block(const int* __restrict__ counts, int* __restrict__ starts,
                             int* __restrict__ bsums, int n) {
    __shared__ int buf[256];
    int i = blockIdx.x * 256 + threadIdx.x;
    int v = (i < n) ? counts[i] : 0;
    buf[threadIdx.x] = v;
    __syncthreads();
#pragma unroll
    for (int off = 1; off < 256; off <<= 1) {
        int t = (threadIdx.x >= off) ? buf[threadIdx.x - off] : 0;
        __syncthreads();
        buf[threadIdx.x] += t;
        __syncthreads();
    }
    if (i < n) starts[i] = buf[threadIdx.x] - v;  // exclusive within block
    if (threadIdx.x == 255) bsums[blockIdx.x] = buf[255];
}

__global__ void k_scan_tops(int* __restrict__ bsums, int nb) {
    __shared__ int buf[256];
    int v = (threadIdx.x < nb) ? bsums[threadIdx.x] : 0;
    buf[threadIdx.x] = v;
    __syncthreads();
#pragma unroll
    for (int off = 1; off < 256; off <<= 1) {
        int t = (threadIdx.x >= off) ? buf[threadIdx.x - off] : 0;
        __syncthreads();
        buf[threadIdx.x] += t;
        __syncthreads();
    }
    if (threadIdx.x < nb) bsums[threadIdx.x] = buf[threadIdx.x] - v;  // exclusive
}

__global__ void k_scan_add(int* __restrict__ starts, const int* __restrict__ bsums,
                           int n, int total) {
    int i = blockIdx.x * 256 + threadIdx.x;
    if (i < n) starts[i] += bsums[blockIdx.x];
    if (i == 0) starts[n] = total;
}

// counting-sort fill with inline norm: packed[pos] = {row, dinv[row]*w*dinv[col]}
__global__ void k_fill_csr(const int* __restrict__ rows, const int* __restrict__ cols,
                           const float* __restrict__ w, const float* __restrict__ dinv,
                           const int* __restrict__ starts, int* __restrict__ cursor,
                           int2* __restrict__ packed, int n_edges) {
    int e = blockIdx.x * blockDim.x + threadIdx.x;
    if (e >= n_edges) return;
    int r = rows[e], c = cols[e];
    float nm = dinv[r] * w[e] * dinv[c];
    int pos = starts[c] + atomicAdd(&cursor[c], 1);
    packed[pos] = make_int2(r, __float_as_int(nm));
}

// C[n, DOUT] = A[n, 128] @ W[128, DOUT], optional ReLU applied to A on load.
template <int DOUT, bool RELU_IN>
__global__ __launch_bounds__(128) void k_gemm(const float* __restrict__ A,
                                              const float* __restrict__ W,
                                              float* __restrict__ C, int n) {
    constexpr int RPB = 32;                 // rows per block
    constexpr int RGROUPS = 128 / DOUT;     // 1 (DOUT=128) or 2 (DOUT=64)
    constexpr int RPT = RPB / RGROUPS;      // rows per thread
    __shared__ float as[RPB][IN_DIM];
    int row0 = blockIdx.x * RPB;
    int j = threadIdx.x % DOUT;
    int rg = threadIdx.x / DOUT;

    for (int t = threadIdx.x; t < RPB * (IN_DIM / 4); t += 128) {
        int r = t >> 5, k4 = (t & 31) << 2;
        float4 v = make_float4(0.f, 0.f, 0.f, 0.f);
        if (row0 + r < n) v = *(const float4*)&A[(size_t)(row0 + r) * IN_DIM + k4];
        if (RELU_IN) {
            v.x = fmaxf(v.x, 0.f); v.y = fmaxf(v.y, 0.f);
            v.z = fmaxf(v.z, 0.f); v.w = fmaxf(v.w, 0.f);
        }
        *(float4*)&as[r][k4] = v;
    }
    __syncthreads();

    float acc[RPT];
#pragma unroll
    for (int r = 0; r < RPT; ++r) acc[r] = 0.f;

    for (int k = 0; k < IN_DIM; k += 4) {
        float w0 = W[(k + 0) * DOUT + j];
        float w1 = W[(k + 1) * DOUT + j];
        float w2 = W[(k + 2) * DOUT + j];
        float w3 = W[(k + 3) * DOUT + j];
#pragma unroll
        for (int r = 0; r < RPT; ++r) {
            float4 a = *(const float4*)&as[rg * RPT + r][k];
            acc[r] = fmaf(a.x, w0, fmaf(a.y, w1, fmaf(a.z, w2, fmaf(a.w, w3, acc[r]))));
        }
    }
#pragma unroll
    for (int r = 0; r < RPT; ++r) {
        int rr = row0 + rg * RPT + r;
        if (rr < n) C[(size_t)rr * DOUT + j] = acc[r];
    }
}

// Gather: one wave handles 64 columns of one node. D=128 -> 2 waves/node.
// out[c][j] = htmp[c][j]*dinv[c]^2 + b[j] + sum_{edges->c} htmp[row][j]*norm
template <int D>
__global__ void k_gather(const float* __restrict__ htmp, const int2* __restrict__ packed,
                         const int* __restrict__ starts, const float* __restrict__ dinv,
                         const float* __restrict__ b, float* __restrict__ out, int n) {
    constexpr int PARTS = D / 64;
    int gw = (int)((blockIdx.x * (size_t)blockDim.x + threadIdx.x) >> 6);
    int node = gw / PARTS;
    int part = gw % PARTS;
    if (node >= n) return;
    int j = part * 64 + (threadIdx.x & 63);
    const float* hj = htmp + j;

    int beg = starts[node], end = starts[node + 1];
    float di = dinv[node];
    float acc = hj[(size_t)node * D] * (di * di) + b[j];

    int p = beg;
    for (; p + 4 <= end; p += 4) {
        int2 e0 = packed[p + 0];
        int2 e1 = packed[p + 1];
        int2 e2 = packed[p + 2];
        int2 e3 = packed[p + 3];
        float v0 = hj[(size_t)e0.x * D];
        float v1 = hj[(size_t)e1.x * D];
        float v2 = hj[(size_t)e2.x * D];
        float v3 = hj[(size_t)e3.x * D];
        acc = fmaf(v0, __int_as_float(e0.y), acc);
        acc = fmaf(v1, __int_as_float(e1.y), acc);
        acc = fmaf(v2, __int_as_float(e2.y), acc);
        acc = fmaf(v3, __int_as_float(e3.y), acc);
    }
    for (; p < end; ++p) {
        int2 e0 = packed[p];
        acc = fmaf(hj[(size_t)e0.x * D], __int_as_float(e0.y), acc);
    }
    out[(size_t)node * D + j] = acc;
}

static inline size_t align_up(size_t x, size_t a) { return (x + a - 1) & ~(a - 1); }

extern "C" void kernel_launch(void* const* d_in, const int* in_sizes, int n_in,
                              void* d_out, int out_size, void* d_ws, size_t ws_size,
                              hipStream_t stream) {
    const float* x  = (const float*)d_in[0];
    const void*  ei = d_in[1];
    const float* ew = (const float*)d_in[2];
    const float* W1 = (const float*)d_in[3];
    const float* b1 = (const float*)d_in[4];
    const float* W2 = (const float*)d_in[5];
    const float* b2 = (const float*)d_in[6];
    float* out = (float*)d_out;

    const int N = N_NODES, E = N_EDGES;

    char* p = (char*)d_ws;
    int*   rows   = (int*)p;   p += align_up((size_t)E * 4, 512);
    int*   cols   = (int*)p;   p += align_up((size_t)E * 4, 512);
    float* deg    = (float*)p; p += align_up((size_t)N * 4, 512);
    float* dinv   = (float*)p; p += align_up((size_t)N * 4, 512);
    int*   counts = (int*)p;   p += align_up((size_t)N * 4, 512);
    int*   starts = (int*)p;   p += align_up((size_t)(N + 1) * 4, 512);
    int*   cursor = (int*)p;   p += align_up((size_t)N * 4, 512);
    int*   bsums  = (int*)p;   p += align_up((size_t)256 * 4, 512);
    int2*  packed = (int2*)p;  p += align_up((size_t)E * 8, 512);
    float* htmp   = (float*)p; p += align_up((size_t)N * IN_DIM * 4, 512);
    float* h1     = (float*)p; p += align_up((size_t)N * HID_DIM * 4, 512);
    (void)ws_size;

    const int B = 256;
    int gE = (E + B - 1) / B;
    int gN = (N + B - 1) / B;
    int nb = (N + 255) / 256;

    // ---- norm + CSR precompute ----
    k_init_nodes<<<gN, B, 0, stream>>>(deg, counts, cursor, N);
    k_edges_hist<<<gE, B, 0, stream>>>(ei, ew, rows, cols, deg, counts, E);
    k_dinv<<<gN, B, 0, stream>>>(deg, dinv, N);
    k_scan_block<<<nb, 256, 0, stream>>>(counts, starts, bsums, N);
    k_scan_tops<<<1, 256, 0, stream>>>(bsums, nb);
    k_scan_add<<<nb, 256, 0, stream>>>(starts, bsums, N, E);
    k_fill_csr<<<gE, B, 0, stream>>>(rows, cols, ew, dinv, starts, cursor, packed, E);

    // ---- layer 1 ----
    int gemm_blocks = (N + 31) / 32;
    k_gemm<HID_DIM, false><<<gemm_blocks, 128, 0, stream>>>(x, W1, htmp, N);
    k_gather<HID_DIM><<<((size_t)N * 2 * 64 + B - 1) / B, B, 0, stream>>>(htmp, packed, starts, dinv, b1, h1, N);
    // ReLU fused into layer-2 GEMM's A-load.

    // ---- layer 2 ----
    k_gemm<OUT_DIM, true><<<gemm_blocks, 128, 0, stream>>>(h1, W2, htmp, N);
    k_gather<OUT_DIM><<<((size_t)N * 64 + B - 1) / B, B, 0, stream>>>(htmp, packed, starts, dinv, b2, out, N);
    (void)out_size; (void)n_in; (void)in_sizes;
}

// Round 4
// 241.001 us; speedup vs baseline: 3.3929x; 1.2034x over previous
//
#include <hip/hip_runtime.h>
#include <hip/hip_bf16.h>
#include <cstdint>

#define N_NODES 50000
#define N_EDGES 640000
#define IN_DIM 128
#define HID_DIM 128
#define OUT_DIM 64

typedef __attribute__((ext_vector_type(8))) short bf16x8;
typedef __attribute__((ext_vector_type(4))) float f32x4;

static __device__ __forceinline__ ushort f32_bf16_rn(float f) {
    uint32_t u = __float_as_uint(f);
    u += 0x7fffu + ((u >> 16) & 1u);
    return (ushort)(u >> 16);
}
static __device__ __forceinline__ float bf16_f32(ushort h) {
    return __uint_as_float(((uint32_t)h) << 16);
}

static __device__ __forceinline__ int detect_i64(const void* p) {
    // int64 edge_index (values < 2^31) => every odd int32 word is a zero high-word.
    const int* q = (const int*)p;
    int odd_or = 0, even_or = 0;
#pragma unroll
    for (int i = 1; i < 64; i += 2) odd_or |= q[i];
#pragma unroll
    for (int i = 0; i < 64; i += 2) even_or |= q[i];
    return (odd_or == 0 && even_or != 0) ? 1 : 0;
}

// deg=1 (self loop), counts=0, cursor=0
__global__ void k_init_nodes(float* __restrict__ deg, int* __restrict__ counts,
                             int* __restrict__ cursor, int n) {
    int i = blockIdx.x * blockDim.x + threadIdx.x;
    if (i < n) { deg[i] = 1.0f; counts[i] = 0; cursor[i] = 0; }
}

// convert edge_index (+layout sniff) -> rows/cols, and histogram deg/counts
__global__ void k_edges_hist(const void* __restrict__ ei, const float* __restrict__ w,
                             int* __restrict__ rows, int* __restrict__ cols,
                             float* __restrict__ deg, int* __restrict__ counts,
                             int n_edges) {
    __shared__ int is64_s;
    if (threadIdx.x == 0) is64_s = detect_i64(ei);
    __syncthreads();
    int e = blockIdx.x * blockDim.x + threadIdx.x;
    if (e >= n_edges) return;
    int r, c;
    if (is64_s) {
        const long long* q = (const long long*)ei;
        r = (int)q[e];
        c = (int)q[e + n_edges];
    } else {
        const int* q = (const int*)ei;
        r = q[e];
        c = q[e + n_edges];
    }
    rows[e] = r;
    cols[e] = c;
    atomicAdd(&deg[c], w[e]);
    atomicAdd(&counts[c], 1);
}

__global__ void k_dinv(const float* __restrict__ deg, float* __restrict__ dinv, int n) {
    int i = blockIdx.x * blockDim.x + threadIdx.x;
    if (i < n) {
        float d = deg[i];
        dinv[i] = d > 0.f ? rsqrtf(d) : 0.f;
    }
}

// ---- hierarchical exclusive scan over counts[n] -> starts[n+1] ----
__global__ void k_scan_block(const int* __restrict__ counts, int* __restrict__ starts,
                             int* __restrict__ bsums, int n) {
    __shared__ int buf[256];
    int i = blockIdx.x * 256 + threadIdx.x;
    int v = (i < n) ? counts[i] : 0;
    buf[threadIdx.x] = v;
    __syncthreads();
#pragma unroll
    for (int off = 1; off < 256; off <<= 1) {
        int t = (threadIdx.x >= off) ? buf[threadIdx.x - off] : 0;
        __syncthreads();
        buf[threadIdx.x] += t;
        __syncthreads();
    }
    if (i < n) starts[i] = buf[threadIdx.x] - v;  // exclusive within block
    if (threadIdx.x == 255) bsums[blockIdx.x] = buf[255];
}

__global__ void k_scan_tops(int* __restrict__ bsums, int nb) {
    __shared__ int buf[256];
    int v = (threadIdx.x < nb) ? bsums[threadIdx.x] : 0;
    buf[threadIdx.x] = v;
    __syncthreads();
#pragma unroll
    for (int off = 1; off < 256; off <<= 1) {
        int t = (threadIdx.x >= off) ? buf[threadIdx.x - off] : 0;
        __syncthreads();
        buf[threadIdx.x] += t;
        __syncthreads();
    }
    if (threadIdx.x < nb) bsums[threadIdx.x] = buf[threadIdx.x] - v;  // exclusive
}

__global__ void k_scan_add(int* __restrict__ starts, const int* __restrict__ bsums,
                           int n, int total) {
    int i = blockIdx.x * 256 + threadIdx.x;
    if (i < n) starts[i] += bsums[blockIdx.x];
    if (i == 0) starts[n] = total;
}

// counting-sort fill with inline norm: packed[pos] = {row, dinv[row]*w*dinv[col]}
__global__ void k_fill_csr(const int* __restrict__ rows, const int* __restrict__ cols,
                           const float* __restrict__ w, const float* __restrict__ dinv,
                           const int* __restrict__ starts, int* __restrict__ cursor,
                           int2* __restrict__ packed, int n_edges) {
    int e = blockIdx.x * blockDim.x + threadIdx.x;
    if (e >= n_edges) return;
    int r = rows[e], c = cols[e];
    float nm = dinv[r] * w[e] * dinv[c];
    int pos = starts[c] + atomicAdd(&cursor[c], 1);
    packed[pos] = make_int2(r, __float_as_int(nm));
}

// Split W (f32 [128][dout]) into hi/lo bf16, packed frag-ready:
// frag = (nt*4 + ks)*64 + g*16 + (j&15), elem e; k = ks*32 + g*8 + e, j = nt*16 + (j&15)
__global__ void k_wsplit(const float* __restrict__ W, ushort* __restrict__ whi,
                         ushort* __restrict__ wlo, int dout) {
    int t = blockIdx.x * blockDim.x + threadIdx.x;
    if (t >= 128 * dout) return;
    int k = t / dout, j = t % dout;
    float w = W[t];
    ushort hi = f32_bf16_rn(w);
    ushort lo = f32_bf16_rn(w - bf16_f32(hi));
    int nt = j >> 4, ks = k >> 5, g = (k >> 3) & 3, e = k & 7;
    int frag = (nt * 4 + ks) * 64 + g * 16 + (j & 15);
    whi[frag * 8 + e] = hi;
    wlo[frag * 8 + e] = lo;
}

// C[n, DOUT] = A[n,128] @ W[128,DOUT] via split-bf16 MFMA (3 products ~ f32 precision).
// Block = 128 threads = 2 waves; each wave owns 32 rows (2 m-tiles), all DOUT cols.
// A-frags loaded straight from global (row = lane&15), converted in-reg; no LDS.
template <int DOUT, bool RELU_IN>
__global__ __launch_bounds__(128) void k_gemm_mfma(const float* __restrict__ A,
                                                   const ushort* __restrict__ whi_u,
                                                   const ushort* __restrict__ wlo_u,
                                                   float* __restrict__ C, int n) {
    constexpr int NT = DOUT / 16;
    const bf16x8* whi = (const bf16x8*)whi_u;
    const bf16x8* wlo = (const bf16x8*)wlo_u;
    int wave = threadIdx.x >> 6, lane = threadIdx.x & 63;
    int g = lane >> 4, rr = lane & 15;
    int row_base = blockIdx.x * 64 + wave * 32;

    f32x4 acc[2][NT];
#pragma unroll
    for (int mt = 0; mt < 2; ++mt)
#pragma unroll
        for (int nt = 0; nt < NT; ++nt) acc[mt][nt] = (f32x4){0.f, 0.f, 0.f, 0.f};

#pragma unroll
    for (int ks = 0; ks < 4; ++ks) {
        bf16x8 ahi[2], alo[2];
#pragma unroll
        for (int mt = 0; mt < 2; ++mt) {
            int row = row_base + mt * 16 + rr;
            float av[8];
            if (row < n) {
                const float* ap = &A[(size_t)row * IN_DIM + ks * 32 + g * 8];
                float4 p0 = *(const float4*)ap;
                float4 p1 = *(const float4*)(ap + 4);
                av[0] = p0.x; av[1] = p0.y; av[2] = p0.z; av[3] = p0.w;
                av[4] = p1.x; av[5] = p1.y; av[6] = p1.z; av[7] = p1.w;
            } else {
#pragma unroll
                for (int e = 0; e < 8; ++e) av[e] = 0.f;
            }
            union { bf16x8 v; ushort u[8]; } H, L;
#pragma unroll
            for (int e = 0; e < 8; ++e) {
                float a = RELU_IN ? fmaxf(av[e], 0.f) : av[e];
                ushort h = f32_bf16_rn(a);
                H.u[e] = h;
                L.u[e] = f32_bf16_rn(a - bf16_f32(h));
            }
            ahi[mt] = H.v;
            alo[mt] = L.v;
        }
#pragma unroll
        for (int nt = 0; nt < NT; ++nt) {
            bf16x8 wh = whi[(nt * 4 + ks) * 64 + lane];
            bf16x8 wl = wlo[(nt * 4 + ks) * 64 + lane];
#pragma unroll
            for (int mt = 0; mt < 2; ++mt) {
                acc[mt][nt] = __builtin_amdgcn_mfma_f32_16x16x32_bf16(ahi[mt], wh, acc[mt][nt], 0, 0, 0);
                acc[mt][nt] = __builtin_amdgcn_mfma_f32_16x16x32_bf16(alo[mt], wh, acc[mt][nt], 0, 0, 0);
                acc[mt][nt] = __builtin_amdgcn_mfma_f32_16x16x32_bf16(ahi[mt], wl, acc[mt][nt], 0, 0, 0);
            }
        }
    }
    // C/D layout (m89-verified): col = lane&15, row = (lane>>4)*4 + reg
#pragma unroll
    for (int mt = 0; mt < 2; ++mt) {
#pragma unroll
        for (int r = 0; r < 4; ++r) {
            int row = row_base + mt * 16 + g * 4 + r;
            if (row < n) {
#pragma unroll
                for (int nt = 0; nt < NT; ++nt)
                    C[(size_t)row * DOUT + nt * 16 + rr] = acc[mt][nt][r];
            }
        }
    }
}

// Gather: one wave handles 64 columns of one node. D=128 -> 2 waves/node.
// out[c][j] = htmp[c][j]*dinv[c]^2 + b[j] + sum_{edges->c} htmp[row][j]*norm
template <int D>
__global__ void k_gather(const float* __restrict__ htmp, const int2* __restrict__ packed,
                         const int* __restrict__ starts, const float* __restrict__ dinv,
                         const float* __restrict__ b, float* __restrict__ out, int n) {
    constexpr int PARTS = D / 64;
    int gw = (int)((blockIdx.x * (size_t)blockDim.x + threadIdx.x) >> 6);
    int node = gw / PARTS;
    int part = gw % PARTS;
    if (node >= n) return;
    int j = part * 64 + (threadIdx.x & 63);
    const float* hj = htmp + j;

    int beg = starts[node], end = starts[node + 1];
    float di = dinv[node];
    float acc = hj[(size_t)node * D] * (di * di) + b[j];

    int p = beg;
    for (; p + 4 <= end; p += 4) {
        int2 e0 = packed[p + 0];
        int2 e1 = packed[p + 1];
        int2 e2 = packed[p + 2];
        int2 e3 = packed[p + 3];
        float v0 = hj[(size_t)e0.x * D];
        float v1 = hj[(size_t)e1.x * D];
        float v2 = hj[(size_t)e2.x * D];
        float v3 = hj[(size_t)e3.x * D];
        acc = fmaf(v0, __int_as_float(e0.y), acc);
        acc = fmaf(v1, __int_as_float(e1.y), acc);
        acc = fmaf(v2, __int_as_float(e2.y), acc);
        acc = fmaf(v3, __int_as_float(e3.y), acc);
    }
    for (; p < end; ++p) {
        int2 e0 = packed[p];
        acc = fmaf(hj[(size_t)e0.x * D], __int_as_float(e0.y), acc);
    }
    out[(size_t)node * D + j] = acc;
}

static inline size_t align_up(size_t x, size_t a) { return (x + a - 1) & ~(a - 1); }

extern "C" void kernel_launch(void* const* d_in, const int* in_sizes, int n_in,
                              void* d_out, int out_size, void* d_ws, size_t ws_size,
                              hipStream_t stream) {
    const float* x  = (const float*)d_in[0];
    const void*  ei = d_in[1];
    const float* ew = (const float*)d_in[2];
    const float* W1 = (const float*)d_in[3];
    const float* b1 = (const float*)d_in[4];
    const float* W2 = (const float*)d_in[5];
    const float* b2 = (const float*)d_in[6];
    float* out = (float*)d_out;

    const int N = N_NODES, E = N_EDGES;

    char* p = (char*)d_ws;
    int*    rows   = (int*)p;    p += align_up((size_t)E * 4, 512);
    int*    cols   = (int*)p;    p += align_up((size_t)E * 4, 512);
    float*  deg    = (float*)p;  p += align_up((size_t)N * 4, 512);
    float*  dinv   = (float*)p;  p += align_up((size_t)N * 4, 512);
    int*    counts = (int*)p;    p += align_up((size_t)N * 4, 512);
    int*    starts = (int*)p;    p += align_up((size_t)(N + 1) * 4, 512);
    int*    cursor = (int*)p;    p += align_up((size_t)N * 4, 512);
    int*    bsums  = (int*)p;    p += align_up((size_t)256 * 4, 512);
    int2*   packed = (int2*)p;   p += align_up((size_t)E * 8, 512);
    float*  htmp   = (float*)p;  p += align_up((size_t)N * IN_DIM * 4, 512);
    float*  h1     = (float*)p;  p += align_up((size_t)N * HID_DIM * 4, 512);
    ushort* w1hi   = (ushort*)p; p += align_up((size_t)128 * HID_DIM * 2, 512);
    ushort* w1lo   = (ushort*)p; p += align_up((size_t)128 * HID_DIM * 2, 512);
    ushort* w2hi   = (ushort*)p; p += align_up((size_t)128 * OUT_DIM * 2, 512);
    ushort* w2lo   = (ushort*)p; p += align_up((size_t)128 * OUT_DIM * 2, 512);
    (void)ws_size;

    const int B = 256;
    int gE = (E + B - 1) / B;
    int gN = (N + B - 1) / B;
    int nb = (N + 255) / 256;

    // ---- norm + CSR precompute ----
    k_init_nodes<<<gN, B, 0, stream>>>(deg, counts, cursor, N);
    k_edges_hist<<<gE, B, 0, stream>>>(ei, ew, rows, cols, deg, counts, E);
    k_dinv<<<gN, B, 0, stream>>>(deg, dinv, N);
    k_scan_block<<<nb, 256, 0, stream>>>(counts, starts, bsums, N);
    k_scan_tops<<<1, 256, 0, stream>>>(bsums, nb);
    k_scan_add<<<nb, 256, 0, stream>>>(starts, bsums, N, E);
    k_fill_csr<<<gE, B, 0, stream>>>(rows, cols, ew, dinv, starts, cursor, packed, E);

    // ---- weight split/pack (tiny) ----
    k_wsplit<<<(128 * HID_DIM + B - 1) / B, B, 0, stream>>>(W1, w1hi, w1lo, HID_DIM);
    k_wsplit<<<(128 * OUT_DIM + B - 1) / B, B, 0, stream>>>(W2, w2hi, w2lo, OUT_DIM);

    // ---- layer 1 ----
    int gemm_blocks = (N + 63) / 64;
    k_gemm_mfma<HID_DIM, false><<<gemm_blocks, 128, 0, stream>>>(x, w1hi, w1lo, htmp, N);
    k_gather<HID_DIM><<<((size_t)N * 2 * 64 + B - 1) / B, B, 0, stream>>>(htmp, packed, starts, dinv, b1, h1, N);
    // ReLU fused into layer-2 GEMM's A-load.

    // ---- layer 2 ----
    k_gemm_mfma<OUT_DIM, true><<<gemm_blocks, 128, 0, stream>>>(h1, w2hi, w2lo, htmp, N);
    k_gather<OUT_DIM><<<((size_t)N * 64 + B - 1) / B, B, 0, stream>>>(htmp, packed, starts, dinv, b2, out, N);
    (void)out_size; (void)n_in; (void)in_sizes;
}

// Round 5
// 167.112 us; speedup vs baseline: 4.8930x; 1.4422x over previous
//
#include <hip/hip_runtime.h>
#include <hip/hip_bf16.h>
#include <cstdint>

#define N_NODES 50000
#define N_EDGES 640000
#define IN_DIM 128
#define HID_DIM 128
#define OUT_DIM 64

typedef __attribute__((ext_vector_type(8))) short bf16x8;
typedef __attribute__((ext_vector_type(4))) float f32x4;

static __device__ __forceinline__ ushort f32_bf16_rn(float f) {
    uint32_t u = __float_as_uint(f);
    u += 0x7fffu + ((u >> 16) & 1u);
    return (ushort)(u >> 16);
}
static __device__ __forceinline__ float bf16_f32(ushort h) {
    return __uint_as_float(((uint32_t)h) << 16);
}

static __device__ __forceinline__ int detect_i64(const void* p) {
    // int64 edge_index (values < 2^31) => every odd int32 word is a zero high-word.
    const int* q = (const int*)p;
    int odd_or = 0, even_or = 0;
#pragma unroll
    for (int i = 1; i < 64; i += 2) odd_or |= q[i];
#pragma unroll
    for (int i = 0; i < 64; i += 2) even_or |= q[i];
    return (odd_or == 0 && even_or != 0) ? 1 : 0;
}

// One pass over edges: decode, store rows/cols, and ONE 64-bit atomic per edge:
// degcnt[c] += (1<<32) | round(w * 2^24).  Returned high word = this edge's rank
// within its destination segment (counting-sort position, order-free).
__global__ void k_edges_rank(const void* __restrict__ ei, const float* __restrict__ w,
                             int* __restrict__ rows, int* __restrict__ cols,
                             int* __restrict__ rank,
                             unsigned long long* __restrict__ degcnt, int n_edges) {
    __shared__ int is64_s;
    if (threadIdx.x == 0) is64_s = detect_i64(ei);
    __syncthreads();
    int e = blockIdx.x * blockDim.x + threadIdx.x;
    if (e >= n_edges) return;
    int r, c;
    if (is64_s) {
        const long long* q = (const long long*)ei;
        r = (int)q[e];
        c = (int)q[e + n_edges];
    } else {
        const int* q = (const int*)ei;
        r = q[e];
        c = q[e + n_edges];
    }
    rows[e] = r;
    cols[e] = c;
    unsigned int wq = (unsigned int)rintf(w[e] * 16777216.0f);  // w * 2^24 fixed-point
    unsigned long long old = atomicAdd(&degcnt[c], (1ull << 32) | (unsigned long long)wq);
    rank[e] = (int)(old >> 32);
}

// Block-level exclusive scan over counts (high word of degcnt); also computes dinv.
__global__ void k_scan_block(const unsigned long long* __restrict__ degcnt,
                             int* __restrict__ starts, int* __restrict__ bsums,
                             float* __restrict__ dinv, int n) {
    __shared__ int buf[256];
    int i = blockIdx.x * 256 + threadIdx.x;
    int v = 0;
    if (i < n) {
        unsigned long long dc = degcnt[i];
        v = (int)(dc >> 32);
        float deg = 1.0f + (float)(unsigned int)(dc & 0xffffffffu) * (1.0f / 16777216.0f);
        dinv[i] = rsqrtf(deg);  // deg >= 1 always (self-loop)
    }
    buf[threadIdx.x] = v;
    __syncthreads();
#pragma unroll
    for (int off = 1; off < 256; off <<= 1) {
        int t = (threadIdx.x >= off) ? buf[threadIdx.x - off] : 0;
        __syncthreads();
        buf[threadIdx.x] += t;
        __syncthreads();
    }
    if (i < n) starts[i] = buf[threadIdx.x] - v;  // exclusive within block
    if (threadIdx.x == 255) bsums[blockIdx.x] = buf[255];
}

__global__ void k_scan_tops(int* __restrict__ bsums, int nb) {
    __shared__ int buf[256];
    int v = (threadIdx.x < nb) ? bsums[threadIdx.x] : 0;
    buf[threadIdx.x] = v;
    __syncthreads();
#pragma unroll
    for (int off = 1; off < 256; off <<= 1) {
        int t = (threadIdx.x >= off) ? buf[threadIdx.x - off] : 0;
        __syncthreads();
        buf[threadIdx.x] += t;
        __syncthreads();
    }
    if (threadIdx.x < nb) bsums[threadIdx.x] = buf[threadIdx.x] - v;  // exclusive
}

__global__ void k_scan_add(int* __restrict__ starts, const int* __restrict__ bsums,
                           int n, int total) {
    int i = blockIdx.x * 256 + threadIdx.x;
    if (i < n) starts[i] += bsums[blockIdx.x];
    if (i == 0) starts[n] = total;
}

// Atomic-free CSR fill: pos = starts[c] + rank[e]; packed = {row, norm}.
__global__ void k_fill(const int* __restrict__ rows, const int* __restrict__ cols,
                       const int* __restrict__ rank, const float* __restrict__ w,
                       const float* __restrict__ dinv, const int* __restrict__ starts,
                       int2* __restrict__ packed, int n_edges) {
    int e = blockIdx.x * blockDim.x + threadIdx.x;
    if (e >= n_edges) return;
    int r = rows[e], c = cols[e];
    float nm = dinv[r] * w[e] * dinv[c];
    int pos = starts[c] + rank[e];
    packed[pos] = make_int2(r, __float_as_int(nm));
}

// Split both W matrices into hi/lo bf16, packed frag-ready, in one launch:
// frag = (nt*4 + ks)*64 + g*16 + (j&15), elem e; k = ks*32 + g*8 + e, j = nt*16 + (j&15)
__global__ void k_wsplit2(const float* __restrict__ W1, ushort* __restrict__ w1hi,
                          ushort* __restrict__ w1lo, const float* __restrict__ W2,
                          ushort* __restrict__ w2hi, ushort* __restrict__ w2lo) {
    int t = blockIdx.x * blockDim.x + threadIdx.x;
    const float* W;
    ushort *whi, *wlo;
    int dout;
    if (t < 128 * HID_DIM) {
        W = W1; whi = w1hi; wlo = w1lo; dout = HID_DIM;
    } else {
        t -= 128 * HID_DIM;
        if (t >= 128 * OUT_DIM) return;
        W = W2; whi = w2hi; wlo = w2lo; dout = OUT_DIM;
    }
    int k = t / dout, j = t % dout;
    float w = W[t];
    ushort hi = f32_bf16_rn(w);
    ushort lo = f32_bf16_rn(w - bf16_f32(hi));
    int nt = j >> 4, ks = k >> 5, g = (k >> 3) & 3, e = k & 7;
    int frag = (nt * 4 + ks) * 64 + g * 16 + (j & 15);
    whi[frag * 8 + e] = hi;
    wlo[frag * 8 + e] = lo;
}

// C[n, DOUT] = A[n,128] @ W[128,DOUT] via split-bf16 MFMA (3 products ~ f32 precision).
// Block = 128 threads = 2 waves; each wave owns 32 rows (2 m-tiles), all DOUT cols.
template <int DOUT, bool RELU_IN>
__global__ __launch_bounds__(128) void k_gemm_mfma(const float* __restrict__ A,
                                                   const ushort* __restrict__ whi_u,
                                                   const ushort* __restrict__ wlo_u,
                                                   float* __restrict__ C, int n) {
    constexpr int NT = DOUT / 16;
    const bf16x8* whi = (const bf16x8*)whi_u;
    const bf16x8* wlo = (const bf16x8*)wlo_u;
    int wave = threadIdx.x >> 6, lane = threadIdx.x & 63;
    int g = lane >> 4, rr = lane & 15;
    int row_base = blockIdx.x * 64 + wave * 32;

    f32x4 acc[2][NT];
#pragma unroll
    for (int mt = 0; mt < 2; ++mt)
#pragma unroll
        for (int nt = 0; nt < NT; ++nt) acc[mt][nt] = (f32x4){0.f, 0.f, 0.f, 0.f};

#pragma unroll
    for (int ks = 0; ks < 4; ++ks) {
        bf16x8 ahi[2], alo[2];
#pragma unroll
        for (int mt = 0; mt < 2; ++mt) {
            int row = row_base + mt * 16 + rr;
            float av[8];
            if (row < n) {
                const float* ap = &A[(size_t)row * IN_DIM + ks * 32 + g * 8];
                float4 p0 = *(const float4*)ap;
                float4 p1 = *(const float4*)(ap + 4);
                av[0] = p0.x; av[1] = p0.y; av[2] = p0.z; av[3] = p0.w;
                av[4] = p1.x; av[5] = p1.y; av[6] = p1.z; av[7] = p1.w;
            } else {
#pragma unroll
                for (int e = 0; e < 8; ++e) av[e] = 0.f;
            }
            union { bf16x8 v; ushort u[8]; } H, L;
#pragma unroll
            for (int e = 0; e < 8; ++e) {
                float a = RELU_IN ? fmaxf(av[e], 0.f) : av[e];
                ushort h = f32_bf16_rn(a);
                H.u[e] = h;
                L.u[e] = f32_bf16_rn(a - bf16_f32(h));
            }
            ahi[mt] = H.v;
            alo[mt] = L.v;
        }
#pragma unroll
        for (int nt = 0; nt < NT; ++nt) {
            bf16x8 wh = whi[(nt * 4 + ks) * 64 + lane];
            bf16x8 wl = wlo[(nt * 4 + ks) * 64 + lane];
#pragma unroll
            for (int mt = 0; mt < 2; ++mt) {
                acc[mt][nt] = __builtin_amdgcn_mfma_f32_16x16x32_bf16(ahi[mt], wh, acc[mt][nt], 0, 0, 0);
                acc[mt][nt] = __builtin_amdgcn_mfma_f32_16x16x32_bf16(alo[mt], wh, acc[mt][nt], 0, 0, 0);
                acc[mt][nt] = __builtin_amdgcn_mfma_f32_16x16x32_bf16(ahi[mt], wl, acc[mt][nt], 0, 0, 0);
            }
        }
    }
    // C/D layout (m89-verified): col = lane&15, row = (lane>>4)*4 + reg
#pragma unroll
    for (int mt = 0; mt < 2; ++mt) {
#pragma unroll
        for (int r = 0; r < 4; ++r) {
            int row = row_base + mt * 16 + g * 4 + r;
            if (row < n) {
#pragma unroll
                for (int nt = 0; nt < NT; ++nt)
                    C[(size_t)row * DOUT + nt * 16 + rr] = acc[mt][nt][r];
            }
        }
    }
}

// Gather, one wave per node. D=128: float2 lanes; D=64: float lanes.
// Unroll-8 so 8 row-fetches are in flight; packed[] accesses are wave-uniform
// (readfirstlane'd bounds -> scalar loads), clamped-index + zeroed-norm tail.
template <int D>
__global__ void k_gather(const float* __restrict__ htmp, const int2* __restrict__ packed,
                         const int* __restrict__ starts, const float* __restrict__ dinv,
                         const float* __restrict__ b, float* __restrict__ out, int n) {
    int node = (int)((blockIdx.x * (size_t)blockDim.x + threadIdx.x) >> 6);
    if (node >= n) return;
    int lane = threadIdx.x & 63;
    int beg = __builtin_amdgcn_readfirstlane(starts[node]);
    int end = __builtin_amdgcn_readfirstlane(starts[node + 1]);
    float di = dinv[node];
    float s = di * di;

    if constexpr (D == 128) {
        int j = lane * 2;
        const float* hj = htmp + j;
        float2 acc = *(const float2*)&hj[(size_t)node * 128];
        acc.x = acc.x * s + b[j];
        acc.y = acc.y * s + b[j + 1];
        for (int p0 = beg; p0 < end; p0 += 8) {
            int2 e[8];
#pragma unroll
            for (int u = 0; u < 8; ++u) {
                int p = p0 + u;
                e[u] = packed[p < end ? p : end - 1];
            }
            float2 v[8];
#pragma unroll
            for (int u = 0; u < 8; ++u)
                v[u] = *(const float2*)&hj[(size_t)e[u].x * 128];
#pragma unroll
            for (int u = 0; u < 8; ++u) {
                float nm = (p0 + u < end) ? __int_as_float(e[u].y) : 0.f;
                acc.x = fmaf(v[u].x, nm, acc.x);
                acc.y = fmaf(v[u].y, nm, acc.y);
            }
        }
        *(float2*)&out[(size_t)node * 128 + j] = acc;
    } else {
        int j = lane;
        const float* hj = htmp + j;
        float acc = hj[(size_t)node * 64] * s + b[j];
        for (int p0 = beg; p0 < end; p0 += 8) {
            int2 e[8];
#pragma unroll
            for (int u = 0; u < 8; ++u) {
                int p = p0 + u;
                e[u] = packed[p < end ? p : end - 1];
            }
            float v[8];
#pragma unroll
            for (int u = 0; u < 8; ++u)
                v[u] = hj[(size_t)e[u].x * 64];
#pragma unroll
            for (int u = 0; u < 8; ++u) {
                float nm = (p0 + u < end) ? __int_as_float(e[u].y) : 0.f;
                acc = fmaf(v[u], nm, acc);
            }
        }
        out[(size_t)node * 64 + j] = acc;
    }
}

static inline size_t align_up(size_t x, size_t a) { return (x + a - 1) & ~(a - 1); }

extern "C" void kernel_launch(void* const* d_in, const int* in_sizes, int n_in,
                              void* d_out, int out_size, void* d_ws, size_t ws_size,
                              hipStream_t stream) {
    const float* x  = (const float*)d_in[0];
    const void*  ei = d_in[1];
    const float* ew = (const float*)d_in[2];
    const float* W1 = (const float*)d_in[3];
    const float* b1 = (const float*)d_in[4];
    const float* W2 = (const float*)d_in[5];
    const float* b2 = (const float*)d_in[6];
    float* out = (float*)d_out;

    const int N = N_NODES, E = N_EDGES;

    char* p = (char*)d_ws;
    int*    rows   = (int*)p;    p += align_up((size_t)E * 4, 512);
    int*    cols   = (int*)p;    p += align_up((size_t)E * 4, 512);
    int*    rank   = (int*)p;    p += align_up((size_t)E * 4, 512);
    unsigned long long* degcnt = (unsigned long long*)p; p += align_up((size_t)N * 8, 512);
    float*  dinv   = (float*)p;  p += align_up((size_t)N * 4, 512);
    int*    starts = (int*)p;    p += align_up((size_t)(N + 1) * 4, 512);
    int*    bsums  = (int*)p;    p += align_up((size_t)256 * 4, 512);
    int2*   packed = (int2*)p;   p += align_up((size_t)E * 8, 512);
    float*  htmp   = (float*)p;  p += align_up((size_t)N * IN_DIM * 4, 512);
    float*  h1     = (float*)p;  p += align_up((size_t)N * HID_DIM * 4, 512);
    ushort* w1hi   = (ushort*)p; p += align_up((size_t)128 * HID_DIM * 2, 512);
    ushort* w1lo   = (ushort*)p; p += align_up((size_t)128 * HID_DIM * 2, 512);
    ushort* w2hi   = (ushort*)p; p += align_up((size_t)128 * OUT_DIM * 2, 512);
    ushort* w2lo   = (ushort*)p; p += align_up((size_t)128 * OUT_DIM * 2, 512);
    (void)ws_size;

    const int B = 256;
    int gE = (E + B - 1) / B;
    int nb = (N + 255) / 256;

    // ---- norm + CSR precompute (single atomic per edge) ----
    hipMemsetAsync(degcnt, 0, (size_t)N * 8, stream);
    k_edges_rank<<<gE, B, 0, stream>>>(ei, ew, rows, cols, rank, degcnt, E);
    k_scan_block<<<nb, 256, 0, stream>>>(degcnt, starts, bsums, dinv, N);
    k_scan_tops<<<1, 256, 0, stream>>>(bsums, nb);
    k_scan_add<<<nb, 256, 0, stream>>>(starts, bsums, N, E);
    k_fill<<<gE, B, 0, stream>>>(rows, cols, rank, ew, dinv, starts, packed, E);

    // ---- weight split/pack (tiny, one launch) ----
    k_wsplit2<<<(128 * (HID_DIM + OUT_DIM) + B - 1) / B, B, 0, stream>>>(W1, w1hi, w1lo, W2, w2hi, w2lo);

    // ---- layer 1 ----
    int gemm_blocks = (N + 63) / 64;
    k_gemm_mfma<HID_DIM, false><<<gemm_blocks, 128, 0, stream>>>(x, w1hi, w1lo, htmp, N);
    k_gather<HID_DIM><<<((size_t)N * 64 + B - 1) / B, B, 0, stream>>>(htmp, packed, starts, dinv, b1, h1, N);
    // ReLU fused into layer-2 GEMM's A-load.

    // ---- layer 2 ----
    k_gemm_mfma<OUT_DIM, true><<<gemm_blocks, 128, 0, stream>>>(h1, w2hi, w2lo, htmp, N);
    k_gather<OUT_DIM><<<((size_t)N * 64 + B - 1) / B, B, 0, stream>>>(htmp, packed, starts, dinv, b2, out, N);
    (void)out_size; (void)n_in; (void)in_sizes;
}

// Round 6
// 138.095 us; speedup vs baseline: 5.9212x; 1.2101x over previous
//
#include <hip/hip_runtime.h>
#include <hip/hip_bf16.h>
#include <cstdint>

#define N_NODES 50000
#define N_EDGES 640000
#define IN_DIM 128
#define HID_DIM 128
#define OUT_DIM 64

constexpr int EDGE_BLOCKS  = (N_EDGES + 255) / 256;                    // 2500
constexpr int GEMM1_BLOCKS = (N_NODES + 127) / 128;                    // 391
constexpr int SCAN_BLOCKS  = (N_NODES + 255) / 256;                    // 196
constexpr int WSPLIT_ELEMS = 128 * (HID_DIM + OUT_DIM);                // 24576

typedef __attribute__((ext_vector_type(8))) short bf16x8;
typedef __attribute__((ext_vector_type(4))) float f32x4;

static __device__ __forceinline__ ushort f32_bf16_rn(float f) {
    uint32_t u = __float_as_uint(f);
    u += 0x7fffu + ((u >> 16) & 1u);
    return (ushort)(u >> 16);
}
static __device__ __forceinline__ float bf16_f32(ushort h) {
    return __uint_as_float(((uint32_t)h) << 16);
}

static __device__ __forceinline__ int detect_i64(const void* p) {
    // int64 edge_index (values < 2^31) => every odd int32 word is a zero high-word.
    const int* q = (const int*)p;
    int odd_or = 0, even_or = 0;
#pragma unroll
    for (int i = 1; i < 64; i += 2) odd_or |= q[i];
#pragma unroll
    for (int i = 0; i < 64; i += 2) even_or |= q[i];
    return (odd_or == 0 && even_or != 0) ? 1 : 0;
}

// Prep: zero degcnt AND split/pack both weight matrices (hi/lo bf16, frag order).
// frag = (nt*4 + ks)*64 + g*16 + (j&15), elem e; k = ks*32 + g*8 + e, j = nt*16 + (j&15)
__global__ void k_prep(unsigned long long* __restrict__ degcnt,
                       const float* __restrict__ W1, ushort* __restrict__ w1hi,
                       ushort* __restrict__ w1lo, const float* __restrict__ W2,
                       ushort* __restrict__ w2hi, ushort* __restrict__ w2lo) {
    int t = blockIdx.x * blockDim.x + threadIdx.x;
    if (t < N_NODES) degcnt[t] = 0ull;
    if (t >= WSPLIT_ELEMS) return;
    const float* W;
    ushort *whi, *wlo;
    int dout, tt = t;
    if (tt < 128 * HID_DIM) {
        W = W1; whi = w1hi; wlo = w1lo; dout = HID_DIM;
    } else {
        tt -= 128 * HID_DIM;
        W = W2; whi = w2hi; wlo = w2lo; dout = OUT_DIM;
    }
    int k = tt / dout, j = tt % dout;
    float w = W[tt];
    ushort hi = f32_bf16_rn(w);
    ushort lo = f32_bf16_rn(w - bf16_f32(hi));
    int nt = j >> 4, ks = k >> 5, g = (k >> 3) & 3, e = k & 7;
    int frag = (nt * 4 + ks) * 64 + g * 16 + (j & 15);
    whi[frag * 8 + e] = hi;
    wlo[frag * 8 + e] = lo;
}

// GEMM1 body: C_bf16[n,128] = A_f32[n,128] @ W1 via split-bf16 (3 MFMA products).
// WAVES waves; each wave owns 32 rows (2 m-tiles).
template <int WAVES>
static __device__ __forceinline__ void gemm1_body(int blk, const float* __restrict__ A,
                                                  const bf16x8* __restrict__ whi,
                                                  const bf16x8* __restrict__ wlo,
                                                  ushort* __restrict__ C, int n) {
    constexpr int NT = HID_DIM / 16;  // 8
    int wave = threadIdx.x >> 6, lane = threadIdx.x & 63;
    int g = lane >> 4, rr = lane & 15;
    int row_base = blk * (32 * WAVES) + wave * 32;

    f32x4 acc[2][NT];
#pragma unroll
    for (int mt = 0; mt < 2; ++mt)
#pragma unroll
        for (int nt = 0; nt < NT; ++nt) acc[mt][nt] = (f32x4){0.f, 0.f, 0.f, 0.f};

#pragma unroll
    for (int ks = 0; ks < 4; ++ks) {
        bf16x8 ahi[2], alo[2];
#pragma unroll
        for (int mt = 0; mt < 2; ++mt) {
            int row = row_base + mt * 16 + rr;
            float av[8];
            if (row < n) {
                const float* ap = &A[(size_t)row * IN_DIM + ks * 32 + g * 8];
                float4 p0 = *(const float4*)ap;
                float4 p1 = *(const float4*)(ap + 4);
                av[0] = p0.x; av[1] = p0.y; av[2] = p0.z; av[3] = p0.w;
                av[4] = p1.x; av[5] = p1.y; av[6] = p1.z; av[7] = p1.w;
            } else {
#pragma unroll
                for (int e = 0; e < 8; ++e) av[e] = 0.f;
            }
            union { bf16x8 v; ushort u[8]; } H, L;
#pragma unroll
            for (int e = 0; e < 8; ++e) {
                ushort h = f32_bf16_rn(av[e]);
                H.u[e] = h;
                L.u[e] = f32_bf16_rn(av[e] - bf16_f32(h));
            }
            ahi[mt] = H.v;
            alo[mt] = L.v;
        }
#pragma unroll
        for (int nt = 0; nt < NT; ++nt) {
            bf16x8 wh = whi[(nt * 4 + ks) * 64 + lane];
            bf16x8 wl = wlo[(nt * 4 + ks) * 64 + lane];
#pragma unroll
            for (int mt = 0; mt < 2; ++mt) {
                acc[mt][nt] = __builtin_amdgcn_mfma_f32_16x16x32_bf16(ahi[mt], wh, acc[mt][nt], 0, 0, 0);
                acc[mt][nt] = __builtin_amdgcn_mfma_f32_16x16x32_bf16(alo[mt], wh, acc[mt][nt], 0, 0, 0);
                acc[mt][nt] = __builtin_amdgcn_mfma_f32_16x16x32_bf16(ahi[mt], wl, acc[mt][nt], 0, 0, 0);
            }
        }
    }
    // C/D layout (m89-verified): col = lane&15, row = (lane>>4)*4 + reg
#pragma unroll
    for (int mt = 0; mt < 2; ++mt) {
#pragma unroll
        for (int r = 0; r < 4; ++r) {
            int row = row_base + mt * 16 + g * 4 + r;
            if (row < n) {
#pragma unroll
                for (int nt = 0; nt < NT; ++nt)
                    C[(size_t)row * HID_DIM + nt * 16 + rr] = f32_bf16_rn(acc[mt][nt][r]);
            }
        }
    }
}

// Fused launch: blocks [0, EDGE_BLOCKS) do the single-atomic edge pass
// (TCC-atomic-bound, ~0% VALU), blocks [EDGE_BLOCKS, +GEMM1_BLOCKS) do GEMM1
// (MFMA-bound) — the two co-schedule on separate pipes.
__global__ __launch_bounds__(256) void k_edges_gemm1(
    const void* __restrict__ ei, const float* __restrict__ ew,
    int* __restrict__ rows, int* __restrict__ cols, int* __restrict__ rank,
    unsigned long long* __restrict__ degcnt,
    const float* __restrict__ x, const ushort* __restrict__ w1hi,
    const ushort* __restrict__ w1lo, ushort* __restrict__ htmp) {
    if (blockIdx.x < EDGE_BLOCKS) {
        __shared__ int is64_s;
        if (threadIdx.x == 0) is64_s = detect_i64(ei);
        __syncthreads();
        int e = blockIdx.x * 256 + threadIdx.x;
        if (e >= N_EDGES) return;
        int r, c;
        if (is64_s) {
            const long long* q = (const long long*)ei;
            r = (int)q[e];
            c = (int)q[e + N_EDGES];
        } else {
            const int* q = (const int*)ei;
            r = q[e];
            c = q[e + N_EDGES];
        }
        rows[e] = r;
        cols[e] = c;
        unsigned int wq = (unsigned int)rintf(ew[e] * 16777216.0f);  // w * 2^24
        unsigned long long old = atomicAdd(&degcnt[c], (1ull << 32) | (unsigned long long)wq);
        rank[e] = (int)(old >> 32);
    } else {
        gemm1_body<4>(blockIdx.x - EDGE_BLOCKS, x, (const bf16x8*)w1hi,
                      (const bf16x8*)w1lo, htmp, N_NODES);
    }
}

// Block-level exclusive scan over counts (high word of degcnt); also computes dinv.
__global__ void k_scan_block(const unsigned long long* __restrict__ degcnt,
                             int* __restrict__ starts, int* __restrict__ bsums,
                             float* __restrict__ dinv, int n) {
    __shared__ int buf[256];
    int i = blockIdx.x * 256 + threadIdx.x;
    int v = 0;
    if (i < n) {
        unsigned long long dc = degcnt[i];
        v = (int)(dc >> 32);
        float deg = 1.0f + (float)(unsigned int)(dc & 0xffffffffu) * (1.0f / 16777216.0f);
        dinv[i] = rsqrtf(deg);  // deg >= 1 always (self-loop)
    }
    buf[threadIdx.x] = v;
    __syncthreads();
#pragma unroll
    for (int off = 1; off < 256; off <<= 1) {
        int t = (threadIdx.x >= off) ? buf[threadIdx.x - off] : 0;
        __syncthreads();
        buf[threadIdx.x] += t;
        __syncthreads();
    }
    if (i < n) starts[i] = buf[threadIdx.x] - v;
    if (threadIdx.x == 255) bsums[blockIdx.x] = buf[255];
}

__global__ void k_scan_tops(int* __restrict__ bsums, int nb) {
    __shared__ int buf[256];
    int v = (threadIdx.x < nb) ? bsums[threadIdx.x] : 0;
    buf[threadIdx.x] = v;
    __syncthreads();
#pragma unroll
    for (int off = 1; off < 256; off <<= 1) {
        int t = (threadIdx.x >= off) ? buf[threadIdx.x - off] : 0;
        __syncthreads();
        buf[threadIdx.x] += t;
        __syncthreads();
    }
    if (threadIdx.x < nb) bsums[threadIdx.x] = buf[threadIdx.x] - v;
}

__global__ void k_scan_add(int* __restrict__ starts, const int* __restrict__ bsums,
                           int n, int total) {
    int i = blockIdx.x * 256 + threadIdx.x;
    if (i < n) starts[i] += bsums[blockIdx.x];
    if (i == 0) starts[n] = total;
}

// Atomic-free CSR fill: pos = starts[c] + rank[e]; packed = {row, norm}.
__global__ void k_fill(const int* __restrict__ rows, const int* __restrict__ cols,
                       const int* __restrict__ rank, const float* __restrict__ w,
                       const float* __restrict__ dinv, const int* __restrict__ starts,
                       int2* __restrict__ packed, int n_edges) {
    int e = blockIdx.x * blockDim.x + threadIdx.x;
    if (e >= n_edges) return;
    int r = rows[e], c = cols[e];
    float nm = dinv[r] * w[e] * dinv[c];
    int pos = starts[c] + rank[e];
    packed[pos] = make_int2(r, __float_as_int(nm));
}

// Gather over bf16 feature rows, one wave per node, unroll-8.
// D=128: lane covers 2 cols (uint = 2 bf16), ReLU'd bf16 output (h1).
// D=64:  lane covers 1 col (ushort), f32 output (final).
template <int D>
__global__ void k_gather_b(const ushort* __restrict__ htmp, const int2* __restrict__ packed,
                           const int* __restrict__ starts, const float* __restrict__ dinv,
                           const float* __restrict__ bias, void* __restrict__ outv, int n) {
    int node = (int)((blockIdx.x * (size_t)blockDim.x + threadIdx.x) >> 6);
    if (node >= n) return;
    int lane = threadIdx.x & 63;
    int beg = __builtin_amdgcn_readfirstlane(starts[node]);
    int end = __builtin_amdgcn_readfirstlane(starts[node + 1]);
    float di = dinv[node];
    float s = di * di;

    if constexpr (D == 128) {
        uint us = ((const uint*)(htmp + (size_t)node * 128))[lane];
        float ax = bf16_f32((ushort)us) * s + bias[lane * 2];
        float ay = bf16_f32((ushort)(us >> 16)) * s + bias[lane * 2 + 1];
        for (int p0 = beg; p0 < end; p0 += 8) {
            int2 e[8];
#pragma unroll
            for (int u = 0; u < 8; ++u) {
                int p = p0 + u;
                e[u] = packed[p < end ? p : end - 1];
            }
            uint v[8];
#pragma unroll
            for (int u = 0; u < 8; ++u)
                v[u] = ((const uint*)(htmp + (size_t)e[u].x * 128))[lane];
#pragma unroll
            for (int u = 0; u < 8; ++u) {
                float nm = (p0 + u < end) ? __int_as_float(e[u].y) : 0.f;
                ax = fmaf(bf16_f32((ushort)v[u]), nm, ax);
                ay = fmaf(bf16_f32((ushort)(v[u] >> 16)), nm, ay);
            }
        }
        // ReLU + pack bf16 pair (h1 feeds layer-2 GEMM directly as exact bf16)
        uint po = (uint)f32_bf16_rn(fmaxf(ax, 0.f)) | ((uint)f32_bf16_rn(fmaxf(ay, 0.f)) << 16);
        ((uint*)((ushort*)outv + (size_t)node * 128))[lane] = po;
    } else {
        float acc = bf16_f32(htmp[(size_t)node * 64 + lane]) * s + bias[lane];
        for (int p0 = beg; p0 < end; p0 += 8) {
            int2 e[8];
#pragma unroll
            for (int u = 0; u < 8; ++u) {
                int p = p0 + u;
                e[u] = packed[p < end ? p : end - 1];
            }
            float v[8];
#pragma unroll
            for (int u = 0; u < 8; ++u)
                v[u] = bf16_f32(htmp[(size_t)e[u].x * 64 + lane]);
#pragma unroll
            for (int u = 0; u < 8; ++u) {
                float nm = (p0 + u < end) ? __int_as_float(e[u].y) : 0.f;
                acc = fmaf(v[u], nm, acc);
            }
        }
        ((float*)outv)[(size_t)node * 64 + lane] = acc;
    }
}

// GEMM2: C_bf16[n,64] = A_bf16[n,128] @ W2, A exact bf16 -> 2 MFMA products.
__global__ __launch_bounds__(128) void k_gemm2(const ushort* __restrict__ A,
                                               const ushort* __restrict__ whi_u,
                                               const ushort* __restrict__ wlo_u,
                                               ushort* __restrict__ C, int n) {
    constexpr int NT = OUT_DIM / 16;  // 4
    const bf16x8* whi = (const bf16x8*)whi_u;
    const bf16x8* wlo = (const bf16x8*)wlo_u;
    int wave = threadIdx.x >> 6, lane = threadIdx.x & 63;
    int g = lane >> 4, rr = lane & 15;
    int row_base = blockIdx.x * 64 + wave * 32;

    f32x4 acc[2][NT];
#pragma unroll
    for (int mt = 0; mt < 2; ++mt)
#pragma unroll
        for (int nt = 0; nt < NT; ++nt) acc[mt][nt] = (f32x4){0.f, 0.f, 0.f, 0.f};

#pragma unroll
    for (int ks = 0; ks < 4; ++ks) {
        bf16x8 a[2];
#pragma unroll
        for (int mt = 0; mt < 2; ++mt) {
            int row = row_base + mt * 16 + rr;
            if (row < n)
                a[mt] = *(const bf16x8*)&A[(size_t)row * HID_DIM + ks * 32 + g * 8];
            else
                a[mt] = (bf16x8){0, 0, 0, 0, 0, 0, 0, 0};
        }
#pragma unroll
        for (int nt = 0; nt < NT; ++nt) {
            bf16x8 wh = whi[(nt * 4 + ks) * 64 + lane];
            bf16x8 wl = wlo[(nt * 4 + ks) * 64 + lane];
#pragma unroll
            for (int mt = 0; mt < 2; ++mt) {
                acc[mt][nt] = __builtin_amdgcn_mfma_f32_16x16x32_bf16(a[mt], wh, acc[mt][nt], 0, 0, 0);
                acc[mt][nt] = __builtin_amdgcn_mfma_f32_16x16x32_bf16(a[mt], wl, acc[mt][nt], 0, 0, 0);
            }
        }
    }
#pragma unroll
    for (int mt = 0; mt < 2; ++mt) {
#pragma unroll
        for (int r = 0; r < 4; ++r) {
            int row = row_base + mt * 16 + g * 4 + r;
            if (row < n) {
#pragma unroll
                for (int nt = 0; nt < NT; ++nt)
                    C[(size_t)row * OUT_DIM + nt * 16 + rr] = f32_bf16_rn(acc[mt][nt][r]);
            }
        }
    }
}

static inline size_t align_up(size_t x, size_t a) { return (x + a - 1) & ~(a - 1); }

extern "C" void kernel_launch(void* const* d_in, const int* in_sizes, int n_in,
                              void* d_out, int out_size, void* d_ws, size_t ws_size,
                              hipStream_t stream) {
    const float* x  = (const float*)d_in[0];
    const void*  ei = d_in[1];
    const float* ew = (const float*)d_in[2];
    const float* W1 = (const float*)d_in[3];
    const float* b1 = (const float*)d_in[4];
    const float* W2 = (const float*)d_in[5];
    const float* b2 = (const float*)d_in[6];
    float* out = (float*)d_out;

    const int N = N_NODES, E = N_EDGES;

    char* p = (char*)d_ws;
    int*    rows   = (int*)p;    p += align_up((size_t)E * 4, 512);
    int*    cols   = (int*)p;    p += align_up((size_t)E * 4, 512);
    int*    rank   = (int*)p;    p += align_up((size_t)E * 4, 512);
    unsigned long long* degcnt = (unsigned long long*)p; p += align_up((size_t)N * 8, 512);
    float*  dinv   = (float*)p;  p += align_up((size_t)N * 4, 512);
    int*    starts = (int*)p;    p += align_up((size_t)(N + 1) * 4, 512);
    int*    bsums  = (int*)p;    p += align_up((size_t)256 * 4, 512);
    int2*   packed = (int2*)p;   p += align_up((size_t)E * 8, 512);
    ushort* htmp1  = (ushort*)p; p += align_up((size_t)N * HID_DIM * 2, 512);
    ushort* h1     = (ushort*)p; p += align_up((size_t)N * HID_DIM * 2, 512);
    ushort* htmp2  = (ushort*)p; p += align_up((size_t)N * OUT_DIM * 2, 512);
    ushort* w1hi   = (ushort*)p; p += align_up((size_t)128 * HID_DIM * 2, 512);
    ushort* w1lo   = (ushort*)p; p += align_up((size_t)128 * HID_DIM * 2, 512);
    ushort* w2hi   = (ushort*)p; p += align_up((size_t)128 * OUT_DIM * 2, 512);
    ushort* w2lo   = (ushort*)p; p += align_up((size_t)128 * OUT_DIM * 2, 512);
    (void)ws_size;

    const int B = 256;
    int gE = (E + B - 1) / B;

    // ---- prep: zero degcnt + split both W (one tiny launch) ----
    k_prep<<<SCAN_BLOCKS, B, 0, stream>>>(degcnt, W1, w1hi, w1lo, W2, w2hi, w2lo);

    // ---- fused: single-atomic edge pass (atomic-bound) + GEMM1 (MFMA-bound) ----
    k_edges_gemm1<<<EDGE_BLOCKS + GEMM1_BLOCKS, B, 0, stream>>>(
        ei, ew, rows, cols, rank, degcnt, x, w1hi, w1lo, htmp1);

    // ---- scan + CSR fill ----
    k_scan_block<<<SCAN_BLOCKS, 256, 0, stream>>>(degcnt, starts, bsums, dinv, N);
    k_scan_tops<<<1, 256, 0, stream>>>(bsums, SCAN_BLOCKS);
    k_scan_add<<<SCAN_BLOCKS, 256, 0, stream>>>(starts, bsums, N, E);
    k_fill<<<gE, B, 0, stream>>>(rows, cols, rank, ew, dinv, starts, packed, E);

    // ---- layer 1 aggregate (bf16 rows, ReLU'd bf16 out) ----
    k_gather_b<HID_DIM><<<((size_t)N * 64 + B - 1) / B, B, 0, stream>>>(
        htmp1, packed, starts, dinv, b1, h1, N);

    // ---- layer 2 ----
    k_gemm2<<<(N + 63) / 64, 128, 0, stream>>>(h1, w2hi, w2lo, htmp2, N);
    k_gather_b<OUT_DIM><<<((size_t)N * 64 + B - 1) / B, B, 0, stream>>>(
        htmp2, packed, starts, dinv, b2, out, N);
    (void)out_size; (void)n_in; (void)in_sizes;
}